// Round 5
// baseline (13000.070 us; speedup 1.0000x reference)
//
#include <hip/hip_runtime.h>
#include <hip/hip_cooperative_groups.h>
#include <math.h>

namespace cg = cooperative_groups;

// Sizes: B=32, S=256, T=256, V=10000, E=512, H=1024, C=1024, SE=8
// in1 = E+SE+C = 1544, 3H = 3072, M = B*T = 8192 (row r = t*32 + b)

__device__ __forceinline__ float sigf(float x) { return 1.0f / (1.0f + __expf(-x)); }

// ---------------- prep: gather ctx/style, build concat vectors, zero b_seq[0] ----------------
__global__ void prep_kernel(const float* __restrict__ enc_output,
                            const int*   __restrict__ enc_len,
                            const int*   __restrict__ styles,
                            const float* __restrict__ style_table,
                            float* __restrict__ xA,     // [32][1032] = [ctx, style]  (for Wp)
                            float* __restrict__ xB,     // [32][1032] = [style, ctx]  (for Wih1[:,E:])
                            float* __restrict__ bseq0)  // [32][1024] zeros
{
    int b = blockIdx.x;
    int tid = threadIdx.x;
    int last = enc_len[b] - 1;
    last = last < 0 ? 0 : (last > 255 ? 255 : last);
    const float* ctx = enc_output + ((size_t)b * 256 + last) * 1024;
    for (int k = tid; k < 1024; k += blockDim.x) {
        float v = ctx[k];
        xA[b * 1032 + k]     = v;
        xB[b * 1032 + 8 + k] = v;
        bseq0[b * 1024 + k]  = 0.0f;
    }
    if (tid < 8) {
        float se = style_table[styles[b] * 8 + tid];
        xA[b * 1032 + 1024 + tid] = se;
        xB[b * 1032 + tid]        = se;
    }
}

// ---------------- generic fp32 GEMM: C[M,N] = A[M,K] * W^T (+bias +rowbase) ----------------
template<int BMODE, int EPI, int GATHER>
__global__ __launch_bounds__(256, 2)
void gemm128(const float* __restrict__ A, int lda,
             const float* __restrict__ W, int ldb,
             const float* __restrict__ bias,
             const float* __restrict__ rowbase,
             const int*   __restrict__ gidx,
             float* __restrict__ Cout,
             int M, int N, int K)
{
    __shared__ float As[8][132];
    __shared__ float Bs[8][132];
    const int tid = threadIdx.x;
    const int r0 = blockIdx.x * 128;
    const int n0 = blockIdx.y * 128;
    const int tx = tid & 15;
    const int ty = tid >> 4;

    float acc[8][8];
#pragma unroll
    for (int i = 0; i < 8; ++i)
#pragma unroll
        for (int j = 0; j < 8; ++j) acc[i][j] = 0.0f;

    const int am  = tid >> 1;
    const int akq = (tid & 1) * 4;
    const bool avalid = (r0 + am) < M;
    const float* arow;
    {
        int r = r0 + am; if (r >= M) r = M - 1;
        if (GATHER) {
            int idx = gidx[(r & 31) * 256 + (r >> 5)];
            arow = A + (size_t)idx * lda;
        } else {
            arow = A + (size_t)r * lda;
        }
    }

    for (int k0 = 0; k0 < K; k0 += 8) {
        float4 av = make_float4(0.f, 0.f, 0.f, 0.f);
        if (avalid) av = *(const float4*)(arow + k0 + akq);

        if (BMODE == 0) {
            const int ncol = tid >> 1;
            const int kq   = (tid & 1) * 4;
            float4 bv = make_float4(0.f, 0.f, 0.f, 0.f);
            int j = n0 + ncol;
            if (j < N) bv = *(const float4*)(W + (size_t)j * ldb + k0 + kq);
            __syncthreads();
            As[akq + 0][am] = av.x; As[akq + 1][am] = av.y;
            As[akq + 2][am] = av.z; As[akq + 3][am] = av.w;
            Bs[kq + 0][ncol] = bv.x; Bs[kq + 1][ncol] = bv.y;
            Bs[kq + 2][ncol] = bv.z; Bs[kq + 3][ncol] = bv.w;
        } else {
            const int kk = tid >> 5;
            const int nq = (tid & 31) * 4;
            float4 bv = make_float4(0.f, 0.f, 0.f, 0.f);
            int j = n0 + nq;
            if (j < N) bv = *(const float4*)(W + (size_t)(k0 + kk) * ldb + j);
            __syncthreads();
            As[akq + 0][am] = av.x; As[akq + 1][am] = av.y;
            As[akq + 2][am] = av.z; As[akq + 3][am] = av.w;
            *(float4*)&Bs[kk][nq] = bv;
        }
        __syncthreads();

#pragma unroll
        for (int kk = 0; kk < 8; ++kk) {
            float4 a0 = *(const float4*)&As[kk][ty * 8];
            float4 a1 = *(const float4*)&As[kk][ty * 8 + 4];
            float4 b0 = *(const float4*)&Bs[kk][tx * 8];
            float4 b1 = *(const float4*)&Bs[kk][tx * 8 + 4];
            float ar[8] = {a0.x, a0.y, a0.z, a0.w, a1.x, a1.y, a1.z, a1.w};
            float br[8] = {b0.x, b0.y, b0.z, b0.w, b1.x, b1.y, b1.z, b1.w};
#pragma unroll
            for (int i = 0; i < 8; ++i)
#pragma unroll
                for (int j = 0; j < 8; ++j)
                    acc[i][j] = fmaf(ar[i], br[j], acc[i][j]);
        }
    }

#pragma unroll
    for (int i = 0; i < 8; ++i) {
        int r = r0 + ty * 8 + i;
        if (r >= M) continue;
        const float* rb = rowbase ? (rowbase + (size_t)(r & 31) * N) : nullptr;
#pragma unroll
        for (int jq = 0; jq < 2; ++jq) {
            int n = n0 + tx * 8 + jq * 4;
            if (n >= N) continue;
            float4 v;
            v.x = acc[i][jq * 4 + 0]; v.y = acc[i][jq * 4 + 1];
            v.z = acc[i][jq * 4 + 2]; v.w = acc[i][jq * 4 + 3];
            if (bias) {
                float4 bz = *(const float4*)(bias + n);
                v.x += bz.x; v.y += bz.y; v.z += bz.z; v.w += bz.w;
            }
            if (rb) {
                float4 rz = *(const float4*)(rb + n);
                v.x += rz.x; v.y += rz.y; v.z += rz.z; v.w += rz.w;
            }
            if (EPI == 2) {
                size_t basei = (size_t)(r >> 5) * (size_t)N * 32 + (size_t)(r & 31);
                Cout[basei + (size_t)(n + 0) * 32] = v.x;
                Cout[basei + (size_t)(n + 1) * 32] = v.y;
                Cout[basei + (size_t)(n + 2) * 32] = v.z;
                Cout[basei + (size_t)(n + 3) * 32] = v.w;
            } else {
                float* crow = (EPI == 0) ? (Cout + (size_t)r * N)
                                         : (Cout + (size_t)((r & 31) * 256 + (r >> 5)) * (size_t)N);
                *(float4*)(crow + n) = v;
            }
        }
    }
}

// ---------------- persistent cooperative scan, LDS-resident weights ----------------
// 256 blocks x 512 threads (1 block/CU). Block bk owns u in {4bk..4bk+3}.
// Thread: ks = tid&7 (k-slice of 128), hi = (tid>>3)&3 (u within block), bq = tid>>5 (b-pair).
// Weights (9 vectors x 4 u x 1024 k = 144 KB) staged once into padded LDS:
//   idx = hi*9512 + vec*1056 + ks*132 + j   (bank = (8hi+4ks+j)%32, 16B-group = (2hi+ks)%8)
// k-reduction via shfl_xor butterfly over ks (lane bits 0..2). Writer lanes: ks==0 -> L1 gates,
// ks==1 -> G2 store, ks==2 -> L2 gates.
__global__ __launch_bounds__(512)
void scan_persistent(const float* __restrict__ gi1T,  // [256][3072][32]
                     float* __restrict__ aSeq,         // [257][32][1024]
                     float* __restrict__ bSeq,         // [257][32][1024]
                     float* __restrict__ gbuf,         // [2][3072][32]
                     const float* __restrict__ Whh1, const float* __restrict__ bhh1,
                     const float* __restrict__ Wih2, const float* __restrict__ bih2,
                     const float* __restrict__ Whh2, const float* __restrict__ bhh2)
{
    cg::grid_group grid = cg::this_grid();
    __shared__ float wlds[38048];   // 152,192 B

    const int tid = threadIdx.x;
    const int ks = tid & 7;
    const int hi = (tid >> 3) & 3;
    const int bq = tid >> 5;             // 0..15
    const int u  = blockIdx.x * 4 + hi;  // 0..1023
    const int b0 = bq * 2, b1 = b0 + 1;

    // ---- stage weights into LDS (once) ----
    {
        const float* srcs[9] = {
            Whh1 + (size_t)u * 1024, Whh1 + (size_t)(1024 + u) * 1024, Whh1 + (size_t)(2048 + u) * 1024,
            Wih2 + (size_t)u * 1024, Wih2 + (size_t)(1024 + u) * 1024, Wih2 + (size_t)(2048 + u) * 1024,
            Whh2 + (size_t)u * 1024, Whh2 + (size_t)(1024 + u) * 1024, Whh2 + (size_t)(2048 + u) * 1024 };
#pragma unroll
        for (int v = 0; v < 9; ++v) {
            const float* s4 = srcs[v] + ks * 128 + bq * 8;
            float4 w0 = *(const float4*)(s4);
            float4 w1 = *(const float4*)(s4 + 4);
            int base = hi * 9512 + v * 1056 + ks * 132 + bq * 8;
            *(float4*)&wlds[base]     = w0;
            *(float4*)&wlds[base + 4] = w1;
        }
    }
    __syncthreads();

    // loop-invariant biases for this u
    const float bh1r = bhh1[u], bh1z = bhh1[1024 + u], bh1n = bhh1[2048 + u];
    const float bi2r = bih2[u], bi2z = bih2[1024 + u], bi2n = bih2[2048 + u];
    const float bh2r = bhh2[u], bh2z = bhh2[1024 + u], bh2n = bhh2[2048 + u];

    const int wbase = hi * 9512 + ks * 132;

    for (int s = 0; s <= 257; ++s) {
        const bool doL1 = (s <= 255);
        const bool doG2 = (s >= 1 && s <= 256);
        const bool doL2 = (s >= 2);
        const float* vinA = aSeq + (size_t)(s <= 256 ? s : 256) * 32768;
        const float* vinB = bSeq + (size_t)(s >= 2 ? s - 2 : 0) * 32768;

        // gate-input prefetch on writer lanes (hidden under the FMA loop)
        float gr0 = 0, gz0 = 0, gn0 = 0, gr1 = 0, gz1 = 0, gn1 = 0, hv0 = 0, hv1 = 0;
        if (ks == 0 && doL1) {
            const float* gi = gi1T + (size_t)s * 98304;
            gr0 = gi[u * 32 + b0]; gz0 = gi[(1024 + u) * 32 + b0]; gn0 = gi[(2048 + u) * 32 + b0];
            gr1 = gi[u * 32 + b1]; gz1 = gi[(1024 + u) * 32 + b1]; gn1 = gi[(2048 + u) * 32 + b1];
            hv0 = vinA[b0 * 1024 + u]; hv1 = vinA[b1 * 1024 + u];
        } else if (ks == 2 && doL2) {
            const float* g2 = gbuf + (size_t)((s + 1) & 1) * 98304;
            gr0 = g2[u * 32 + b0]; gz0 = g2[(1024 + u) * 32 + b0]; gn0 = g2[(2048 + u) * 32 + b0];
            gr1 = g2[u * 32 + b1]; gz1 = g2[(1024 + u) * 32 + b1]; gn1 = g2[(2048 + u) * 32 + b1];
            hv0 = vinB[b0 * 1024 + u]; hv1 = vinB[b1 * 1024 + u];
        }

        float aA0[6] = {0.f, 0.f, 0.f, 0.f, 0.f, 0.f};
        float aA1[6] = {0.f, 0.f, 0.f, 0.f, 0.f, 0.f};
        float aC0[3] = {0.f, 0.f, 0.f};
        float aC1[3] = {0.f, 0.f, 0.f};

        if (doL1 || doG2) {
            const float* h0 = vinA + b0 * 1024 + ks * 128;
            const float* h1 = vinA + b1 * 1024 + ks * 128;
#pragma unroll 8
            for (int j = 0; j < 128; j += 4) {
                float4 x0 = *(const float4*)(h0 + j);
                float4 x1 = *(const float4*)(h1 + j);
#pragma unroll
                for (int v = 0; v < 6; ++v) {
                    float4 w = *(const float4*)&wlds[wbase + v * 1056 + j];
                    aA0[v] = fmaf(x0.x, w.x, fmaf(x0.y, w.y, fmaf(x0.z, w.z, fmaf(x0.w, w.w, aA0[v]))));
                    aA1[v] = fmaf(x1.x, w.x, fmaf(x1.y, w.y, fmaf(x1.z, w.z, fmaf(x1.w, w.w, aA1[v]))));
                }
            }
        }
        if (doL2) {
            const float* h0 = vinB + b0 * 1024 + ks * 128;
            const float* h1 = vinB + b1 * 1024 + ks * 128;
#pragma unroll 8
            for (int j = 0; j < 128; j += 4) {
                float4 x0 = *(const float4*)(h0 + j);
                float4 x1 = *(const float4*)(h1 + j);
#pragma unroll
                for (int v = 0; v < 3; ++v) {
                    float4 w = *(const float4*)&wlds[wbase + (6 + v) * 1056 + j];
                    aC0[v] = fmaf(x0.x, w.x, fmaf(x0.y, w.y, fmaf(x0.z, w.z, fmaf(x0.w, w.w, aC0[v]))));
                    aC1[v] = fmaf(x1.x, w.x, fmaf(x1.y, w.y, fmaf(x1.z, w.z, fmaf(x1.w, w.w, aC1[v]))));
                }
            }
        }

        // butterfly reduce over ks (lane bits 0..2)
#pragma unroll
        for (int d = 1; d < 8; d <<= 1) {
#pragma unroll
            for (int v = 0; v < 6; ++v) {
                aA0[v] += __shfl_xor(aA0[v], d);
                aA1[v] += __shfl_xor(aA1[v], d);
            }
#pragma unroll
            for (int v = 0; v < 3; ++v) {
                aC0[v] += __shfl_xor(aC0[v], d);
                aC1[v] += __shfl_xor(aC1[v], d);
            }
        }

        if (ks == 0 && doL1) {
            float r0 = sigf(gr0 + aA0[0] + bh1r);
            float z0 = sigf(gz0 + aA0[1] + bh1z);
            float n0 = tanhf(gn0 + r0 * (aA0[2] + bh1n));
            float r1 = sigf(gr1 + aA1[0] + bh1r);
            float z1 = sigf(gz1 + aA1[1] + bh1z);
            float n1 = tanhf(gn1 + r1 * (aA1[2] + bh1n));
            float* outp = aSeq + (size_t)(s + 1) * 32768;
            outp[b0 * 1024 + u] = (1.0f - z0) * n0 + z0 * hv0;
            outp[b1 * 1024 + u] = (1.0f - z1) * n1 + z1 * hv1;
        } else if (ks == 1 && doG2) {
            float* g2 = gbuf + (size_t)(s & 1) * 98304;
            g2[u * 32 + b0]            = aA0[3] + bi2r;
            g2[(1024 + u) * 32 + b0]   = aA0[4] + bi2z;
            g2[(2048 + u) * 32 + b0]   = aA0[5] + bi2n;
            g2[u * 32 + b1]            = aA1[3] + bi2r;
            g2[(1024 + u) * 32 + b1]   = aA1[4] + bi2z;
            g2[(2048 + u) * 32 + b1]   = aA1[5] + bi2n;
        } else if (ks == 2 && doL2) {
            float r0 = sigf(gr0 + aC0[0] + bh2r);
            float z0 = sigf(gz0 + aC0[1] + bh2z);
            float n0 = tanhf(gn0 + r0 * (aC0[2] + bh2n));
            float r1 = sigf(gr1 + aC1[0] + bh2r);
            float z1 = sigf(gz1 + aC1[1] + bh2z);
            float n1 = tanhf(gn1 + r1 * (aC1[2] + bh2n));
            float* outp = bSeq + (size_t)(s - 1) * 32768;
            outp[b0 * 1024 + u] = (1.0f - z0) * n0 + z0 * hv0;
            outp[b1 * 1024 + u] = (1.0f - z1) * n1 + z1 * hv1;
        }

        grid.sync();
    }
}

// ---------------- fallback: per-step fused kernel (verified in round 2) ----------------
__global__ __launch_bounds__(512, 6)
void fused_step(const float* __restrict__ aCur,
                float* __restrict__ aNext,
                const float* __restrict__ bPrev,
                float* __restrict__ bCur,
                const float* __restrict__ gi1T,
                float* __restrict__ gi2W,
                const float* __restrict__ gi2R,
                const float* __restrict__ Whh1, const float* __restrict__ bhh1,
                const float* __restrict__ Wih2, const float* __restrict__ bih2,
                const float* __restrict__ Whh2, const float* __restrict__ bhh2,
                int doL1, int doG2, int doL2)
{
    const int role = blockIdx.x >> 8;
    if (role == 0) { if (!doL1) return; }
    else if (role == 1) { if (!doG2) return; }
    else { if (!doL2) return; }

    __shared__ float hp[32][260];
    __shared__ float part[4][32][4][3];

    const int tid = threadIdx.x;
    const int b  = tid & 31;
    const int hi = (tid >> 5) & 3;
    const int ks = tid >> 7;
    const int h  = (blockIdx.x & 255) * 4 + hi;

    const float* vin = (role == 2) ? bPrev : aCur;
    const float* W   = (role == 0) ? Whh1 : (role == 1 ? Wih2 : Whh2);

    const float* w0 = W + (size_t)h * 1024;
    const float* w1 = W + (size_t)(1024 + h) * 1024;
    const float* w2 = W + (size_t)(2048 + h) * 1024;

    const int sb = tid >> 4;
    const int sc = tid & 15;

    float acc0 = 0.f, acc1 = 0.f, acc2 = 0.f;

    for (int kt = 0; kt < 4; ++kt) {
        const int kbase = kt * 256;
        __syncthreads();
        {
            const float4* src = (const float4*)(vin + sb * 1024 + kbase);
#pragma unroll
            for (int q = 0; q < 4; ++q) {
                float4 v = src[sc + q * 16];
                *(float4*)&hp[sb][(sc + q * 16) * 4] = v;
            }
        }
        __syncthreads();
        const float* ap  = &hp[b][ks * 64];
        const float* wk0 = w0 + kbase + ks * 64;
        const float* wk1 = w1 + kbase + ks * 64;
        const float* wk2 = w2 + kbase + ks * 64;
#pragma unroll
        for (int k = 0; k < 64; k += 4) {
            float4 a4 = *(const float4*)(ap + k);
            float4 x0 = *(const float4*)(wk0 + k);
            float4 x1 = *(const float4*)(wk1 + k);
            float4 x2 = *(const float4*)(wk2 + k);
            acc0 = fmaf(a4.x, x0.x, fmaf(a4.y, x0.y, fmaf(a4.z, x0.z, fmaf(a4.w, x0.w, acc0))));
            acc1 = fmaf(a4.x, x1.x, fmaf(a4.y, x1.y, fmaf(a4.z, x1.z, fmaf(a4.w, x1.w, acc1))));
            acc2 = fmaf(a4.x, x2.x, fmaf(a4.y, x2.y, fmaf(a4.z, x2.z, fmaf(a4.w, x2.w, acc2))));
        }
    }
    part[ks][b][hi][0] = acc0;
    part[ks][b][hi][1] = acc1;
    part[ks][b][hi][2] = acc2;
    __syncthreads();
    if (ks == 0) {
        float s0 = part[0][b][hi][0] + part[1][b][hi][0] + part[2][b][hi][0] + part[3][b][hi][0];
        float s1 = part[0][b][hi][1] + part[1][b][hi][1] + part[2][b][hi][1] + part[3][b][hi][1];
        float s2 = part[0][b][hi][2] + part[1][b][hi][2] + part[2][b][hi][2] + part[3][b][hi][2];
        if (role == 1) {
            gi2W[(size_t)h * 32 + b]          = s0 + bih2[h];
            gi2W[(size_t)(1024 + h) * 32 + b] = s1 + bih2[1024 + h];
            gi2W[(size_t)(2048 + h) * 32 + b] = s2 + bih2[2048 + h];
        } else {
            const float* bb = (role == 0) ? bhh1 : bhh2;
            const float* gi = (role == 0) ? gi1T : gi2R;
            float ghr = s0 + bb[h];
            float ghz = s1 + bb[1024 + h];
            float ghn = s2 + bb[2048 + h];
            float gir = gi[(size_t)h * 32 + b];
            float giz = gi[(size_t)(1024 + h) * 32 + b];
            float gin = gi[(size_t)(2048 + h) * 32 + b];
            float r  = sigf(gir + ghr);
            float z  = sigf(giz + ghz);
            float nn = tanhf(gin + r * ghn);
            float hv = vin[b * 1024 + h];
            float* outp = (role == 0) ? aNext : bCur;
            outp[b * 1024 + h] = (1.0f - z) * nn + z * hv;
        }
    }
}

// ---------------- fused log-softmax tail: lse, gather log-prob, argmax ----------------
__global__ __launch_bounds__(256)
void softmax_tail(const float* __restrict__ logits,  // [(b*256+t)][10000]
                  const int*   __restrict__ dec_out, // [32][256] flat = p
                  float* __restrict__ lp,
                  float* __restrict__ pred)
{
    const int p = blockIdx.x;
    const int tid = threadIdx.x;
    const float* row = logits + (size_t)p * 10000;

    float m = -INFINITY, s = 0.0f;
    int am = 0;
    for (int q = tid; q < 2500; q += 256) {
        float4 v = *(const float4*)(row + q * 4);
        float xs[4] = {v.x, v.y, v.z, v.w};
#pragma unroll
        for (int c = 0; c < 4; ++c) {
            float x = xs[c];
            if (x > m) {
                s = s * __expf(m - x) + 1.0f;
                m = x;
                am = q * 4 + c;
            } else {
                s += __expf(x - m);
            }
        }
    }
    __shared__ float sm[256];
    __shared__ float ss[256];
    __shared__ int   sa[256];
    sm[tid] = m; ss[tid] = s; sa[tid] = am;
    __syncthreads();
    for (int w = 128; w > 0; w >>= 1) {
        if (tid < w) {
            float m1 = sm[tid],     s1 = ss[tid];     int a1 = sa[tid];
            float m2 = sm[tid + w], s2 = ss[tid + w]; int a2 = sa[tid + w];
            float M2 = fmaxf(m1, m2);
            float S2 = s1 * __expf(m1 - M2) + s2 * __expf(m2 - M2);
            int A2;
            if (m1 > m2) A2 = a1;
            else if (m2 > m1) A2 = a2;
            else A2 = (a1 < a2) ? a1 : a2;
            sm[tid] = M2; ss[tid] = S2; sa[tid] = A2;
        }
        __syncthreads();
    }
    if (tid == 0) {
        float lse = sm[0] + logf(ss[0]);
        int tok = dec_out[p];
        lp[p]   = row[tok] - lse;
        pred[p] = (float)sa[0];
    }
}

extern "C" void kernel_launch(void* const* d_in, const int* in_sizes, int n_in,
                              void* d_out, int out_size, void* d_ws, size_t ws_size,
                              hipStream_t stream)
{
    const float* enc_output  = (const float*)d_in[0];
    const int*   enc_len     = (const int*)  d_in[1];
    const int*   styles      = (const int*)  d_in[2];
    const int*   dec_in      = (const int*)  d_in[3];
    const int*   dec_out     = (const int*)  d_in[4];
    const float* emb_table   = (const float*)d_in[5];
    const float* style_table = (const float*)d_in[6];
    const float* Wp   = (const float*)d_in[7];
    const float* bp   = (const float*)d_in[8];
    const float* Wih1 = (const float*)d_in[9];
    const float* Whh1 = (const float*)d_in[10];
    const float* bih1 = (const float*)d_in[11];
    const float* bhh1 = (const float*)d_in[12];
    const float* Wih2 = (const float*)d_in[13];
    const float* Whh2 = (const float*)d_in[14];
    const float* bih2 = (const float*)d_in[15];
    const float* bhh2 = (const float*)d_in[16];
    const float* Wout = (const float*)d_in[17];
    const float* bout = (const float*)d_in[18];

    float* out = (float*)d_out;

    // Scratch inside logits region of d_out (all dead before logits GEMM overwrites):
    float* gi1T  = out;                  // [256][3072][32] = 25,165,824 f
    float* aSeq  = out + 25165824;       // [257][32][1024] =  8,421,376 f
    float* base1 = out + 33587200;       // [32][3072]
    float* xA    = out + 33685504;       // [32][1032]
    float* xB    = out + 33718528;       // [32][1032]
    float* gbuf  = out + 33751552;       // [2][3072][32] = 196,608 f (ends 33,948,160)
    // b_seq survives while logits are written -> d_ws:
    float* bSeq  = (float*)d_ws;         // [257][32][1024] = 33.7 MB

    float* logitsOut = out;              // [32][256][10000]
    float* lpOut     = out + 81920000;   // [32][256]
    float* predOut   = out + 81928192;   // [32][256]

    // Phase 0: gather + concat vectors + zero b_seq slot 0
    prep_kernel<<<32, 256, 0, stream>>>(enc_output, enc_len, styles, style_table, xA, xB, bSeq);

    // h0 = xA @ Wp^T + bp  -> a_seq slot 0
    gemm128<0, 0, 0><<<dim3(1, 8), 256, 0, stream>>>(xA, 1032, Wp, 1032, bp, nullptr, nullptr,
                                                     aSeq, 32, 1024, 1032);
    // base1 = xB @ Wih1[:, 512:]^T + bih1
    gemm128<0, 0, 0><<<dim3(1, 24), 256, 0, stream>>>(xB, 1032, Wih1 + 512, 1544, bih1, nullptr, nullptr,
                                                      base1, 32, 3072, 1032);
    // gi1T[t][col][b] = (emb[dec_in] @ Wih1[:, :512]^T + base1[b]) transposed per t
    gemm128<0, 2, 1><<<dim3(64, 24), 256, 0, stream>>>(emb_table, 512, Wih1, 1544, nullptr, base1, dec_in,
                                                       gi1T, 8192, 3072, 512);

    // ---- scan: cooperative persistent kernel if supported, else verified per-step loop ----
    int dev = 0;
    (void)hipGetDevice(&dev);
    int coopAttr = 0;
    (void)hipDeviceGetAttribute(&coopAttr, hipDeviceAttributeCooperativeLaunch, dev);
    int numCU = 0;
    (void)hipDeviceGetAttribute(&numCU, hipDeviceAttributeMultiprocessorCount, dev);
    int maxB = 0;
    (void)hipOccupancyMaxActiveBlocksPerMultiprocessor(&maxB, scan_persistent, 512, 0);

    bool coopDone = false;
    if (coopAttr && maxB >= 1 && numCU >= 256) {
        const float* gi1T_c = gi1T;
        float* aSeq_c = aSeq;
        float* bSeq_c = bSeq;
        float* gbuf_c = gbuf;
        const float* Whh1_c = Whh1; const float* bhh1_c = bhh1;
        const float* Wih2_c = Wih2; const float* bih2_c = bih2;
        const float* Whh2_c = Whh2; const float* bhh2_c = bhh2;
        void* args[] = { (void*)&gi1T_c, (void*)&aSeq_c, (void*)&bSeq_c, (void*)&gbuf_c,
                         (void*)&Whh1_c, (void*)&bhh1_c, (void*)&Wih2_c, (void*)&bih2_c,
                         (void*)&Whh2_c, (void*)&bhh2_c };
        hipError_t e = hipLaunchCooperativeKernel((const void*)scan_persistent, dim3(256), dim3(512),
                                                  args, 0, stream);
        coopDone = (e == hipSuccess);
    }
    if (!coopDone) {
        for (int s = 0; s <= 257; ++s) {
            int doL1 = (s <= 255);
            int doG2 = (s >= 1 && s <= 256);
            int doL2 = (s >= 2);
            const float* aCur = aSeq + (size_t)(s <= 256 ? s : 256) * 32768;
            float* aNext      = aSeq + (size_t)(s <= 255 ? s + 1 : 256) * 32768;
            const float* bPrev = bSeq + (size_t)(s >= 2 ? s - 2 : 0) * 32768;
            float* bCur        = bSeq + (size_t)(s >= 2 ? s - 1 : 0) * 32768;
            const float* g1 = gi1T + (size_t)(s <= 255 ? s : 0) * 98304;
            float* g2w = gbuf + (size_t)(s & 1) * 98304;
            const float* g2r = gbuf + (size_t)((s + 1) & 1) * 98304;
            fused_step<<<768, 512, 0, stream>>>(aCur, aNext, bPrev, bCur, g1, g2w, g2r,
                                                Whh1, bhh1, Wih2, bih2, Whh2, bhh2,
                                                doL1, doG2, doL2);
        }
    }

    // logits = b_seq[1..256] @ Wout + bout, written in [b][t][v] order
    gemm128<1, 1, 0><<<dim3(64, 79), 256, 0, stream>>>(bSeq + 32768, 1024, Wout, 10000, bout, nullptr, nullptr,
                                                       logitsOut, 8192, 10000, 1024);
    // log-softmax gather + argmax
    softmax_tail<<<8192, 256, 0, stream>>>(logitsOut, dec_out, lpOut, predOut);
}